// Round 4
// baseline (828.380 us; speedup 1.0000x reference)
//
#include <hip/hip_runtime.h>
#include <math.h>

#define NEGF -1000000000.0f
#define EPSF 1e-7f

// B=32, T=256, IN=64, H=128, 4H=512, TOP_K=5

__device__ __forceinline__ float fsigmoid(float x) {
  return 1.0f / (1.0f + __expf(-x));               // overflow -> correct limit
}
__device__ __forceinline__ float ftanh(float x) {
  return 1.0f - 2.0f / (1.0f + __expf(2.0f * x));  // limits +-1: correct
}

// Kernel 1: xw[b][t][g] = sum_k x[b][t][k] * W_ih[g][k] + (b_ih[g]+b_hh[g])
// grid (16, 32) = (T/16, B), block 512 (one thread per gate).
// waves_per_eu(4,4): register budget 128 so the 64-float W_ih row stays
// in VGPRs (16 named float4s) instead of spilling to scratch.
__global__
__attribute__((amdgpu_flat_work_group_size(512, 512), amdgpu_waves_per_eu(4, 4)))
void xw_kernel(
    const float* __restrict__ x, const float* __restrict__ W_ih,
    const float* __restrict__ b_ih, const float* __restrict__ b_hh,
    float* __restrict__ xw)
{
  const int TT = 16;
  const int t0 = blockIdx.x * TT;
  const int b  = blockIdx.y;
  __shared__ float sx[16][64];
  for (int idx = threadIdx.x; idx < TT * 64; idx += 512) {
    int tt = idx >> 6, k = idx & 63;
    sx[tt][k] = x[(size_t)(b * 256 + t0 + tt) * 64 + k];
  }
  const int g = threadIdx.x;
  const float4* wr = (const float4*)(W_ih + g * 64);
  float4 w0 = wr[0], w1 = wr[1], w2 = wr[2],  w3 = wr[3],
         w4 = wr[4], w5 = wr[5], w6 = wr[6],  w7 = wr[7],
         w8 = wr[8], w9 = wr[9], w10 = wr[10], w11 = wr[11],
         w12 = wr[12], w13 = wr[13], w14 = wr[14], w15 = wr[15];
  const float bias = b_ih[g] + b_hh[g];
  __syncthreads();
  for (int tt = 0; tt < TT; ++tt) {
    const float4* sx4 = (const float4*)(&sx[tt][0]);
    float a0 = bias, a1 = 0.0f, a2 = 0.0f, a3 = 0.0f;
#define XSTEP(q) { float4 hv = sx4[q]; \
    a0 = fmaf(w##q.x, hv.x, a0); a1 = fmaf(w##q.y, hv.y, a1); \
    a2 = fmaf(w##q.z, hv.z, a2); a3 = fmaf(w##q.w, hv.w, a3); }
    XSTEP(0) XSTEP(1) XSTEP(2) XSTEP(3) XSTEP(4) XSTEP(5) XSTEP(6) XSTEP(7)
    XSTEP(8) XSTEP(9) XSTEP(10) XSTEP(11) XSTEP(12) XSTEP(13) XSTEP(14) XSTEP(15)
#undef XSTEP
    xw[(size_t)(b * 256 + t0 + tt) * 512 + g] = (a0 + a1) + (a2 + a3);
  }
}

// Kernel 2: full recurrence, one block per batch element, 512 threads.
// Thread g owns gate g completely: 128 W_hh weights in 32 NAMED float4s.
// waves_per_eu(2,2) pins the allocator's budget at 256 VGPRs (default
// heuristic targets 8 waves/EU = 64 VGPRs -> spilled all weights to
// scratch in rounds 1-3; LDS of 137 KB already limits us to 1 block/CU,
// so 2 waves/EU costs nothing).
// h_old history lives entirely in LDS (257*128 fp32 = 131 KB).
__global__
__attribute__((amdgpu_flat_work_group_size(512, 512), amdgpu_waves_per_eu(2, 2)))
void lstm_attn(
    const float* __restrict__ xw, const float* __restrict__ W_hh,
    const float* __restrict__ w_t, float* __restrict__ out)
{
  const int b    = blockIdx.x;
  const int tid  = threadIdx.x;
  const int lane = tid & 63;
  const int wid  = tid >> 6;
  const int g    = tid;

  __shared__ float ho[257 * 128];     // h history (131584 B)
  __shared__ float sh_part[512];      // finished gate preactivations
  __shared__ float sh_h[128];
  __shared__ float sh_hcell[128];
  __shared__ float sh_d[257];
  __shared__ float sh_wa[128];
  __shared__ float sh_wb[128];
  __shared__ float sh_top5[5];
  __shared__ float sh_redA[2];
  __shared__ float sh_redW[4];
  __shared__ float sh_redD[2];
  __shared__ int   sh_nnz;
  __shared__ int   sh_cidx[8];
  __shared__ float sh_cw[8];

  // one-time weight load: 32 named float4 = 128 VGPRs, no spillable array
  const float4* wr = (const float4*)(W_hh + (size_t)g * 128);
  float4 w0 = wr[0],   w1 = wr[1],   w2 = wr[2],   w3 = wr[3],
         w4 = wr[4],   w5 = wr[5],   w6 = wr[6],   w7 = wr[7],
         w8 = wr[8],   w9 = wr[9],   w10 = wr[10], w11 = wr[11],
         w12 = wr[12], w13 = wr[13], w14 = wr[14], w15 = wr[15],
         w16 = wr[16], w17 = wr[17], w18 = wr[18], w19 = wr[19],
         w20 = wr[20], w21 = wr[21], w22 = wr[22], w23 = wr[23],
         w24 = wr[24], w25 = wr[25], w26 = wr[26], w27 = wr[27],
         w28 = wr[28], w29 = wr[29], w30 = wr[30], w31 = wr[31];

  if (tid < 128) {
    sh_h[tid]  = 0.0f;
    sh_wa[tid] = w_t[tid];
    sh_wb[tid] = w_t[128 + tid];
    ho[tid]    = 0.0f;                // row 0 = h(-1) = zeros
  }
  if (tid == 0) {
    sh_d[0] = 0.0f;                   // tanh(0)·w_b
    sh_top5[0] = 0.0f;
    sh_top5[1] = sh_top5[2] = sh_top5[3] = sh_top5[4] = NEGF;
  }
  float c_reg = 0.0f;                 // c[j] lives in thread j (tid<128)
  __syncthreads();

  const float* xwb = xw + (size_t)b * 256 * 512;
  float xcur = xwb[g];                // prefetched xw for step 0

  for (int i = 0; i < 256; ++i) {
    const int rem = i + 1;

    // ---- Phase A: gate preactivation (128 FMAs from named-VGPR weights) ----
    float a0 = xcur, a1 = 0.0f, a2 = 0.0f, a3 = 0.0f;
    if (i < 255) xcur = xwb[(size_t)(i + 1) * 512 + g];   // prefetch next step
    const float4* hh4 = (const float4*)sh_h;
#define ASTEP(j) { float4 hv = hh4[j]; \
    a0 = fmaf(w##j.x, hv.x, a0); a1 = fmaf(w##j.y, hv.y, a1); \
    a2 = fmaf(w##j.z, hv.z, a2); a3 = fmaf(w##j.w, hv.w, a3); }
    ASTEP(0)  ASTEP(1)  ASTEP(2)  ASTEP(3)  ASTEP(4)  ASTEP(5)  ASTEP(6)  ASTEP(7)
    ASTEP(8)  ASTEP(9)  ASTEP(10) ASTEP(11) ASTEP(12) ASTEP(13) ASTEP(14) ASTEP(15)
    ASTEP(16) ASTEP(17) ASTEP(18) ASTEP(19) ASTEP(20) ASTEP(21) ASTEP(22) ASTEP(23)
    ASTEP(24) ASTEP(25) ASTEP(26) ASTEP(27) ASTEP(28) ASTEP(29) ASTEP(30) ASTEP(31)
#undef ASTEP
    sh_part[g] = (a0 + a1) + (a2 + a3);
    __syncthreads();                                        // S1

    // ---- Phase B: LSTM cell + a = tanh(h_cell)·w_a partial ----
    if (tid == 0) sh_nnz = 0;
    float pa = 0.0f;
    if (tid < 128) {
      float gi = fsigmoid(sh_part[tid      ]);
      float gf = fsigmoid(sh_part[tid + 128]);
      float gG = ftanh   (sh_part[tid + 256]);
      float go = fsigmoid(sh_part[tid + 384]);
      c_reg = gf * c_reg + gi * gG;
      float hc = go * ftanh(c_reg);
      sh_hcell[tid] = hc;
      pa = ftanh(hc) * sh_wa[tid];
    }
    if (wid < 2) {
      #pragma unroll
      for (int off = 32; off > 0; off >>= 1) pa += __shfl_down(pa, off, 64);
      if (lane == 0) sh_redA[wid] = pa;
    }
    __syncthreads();                                        // S2

    // ---- Phase C: scores, sparse-candidate collection (unnormalized) ----
    const float a     = sh_redA[0] + sh_redA[1];
    const float delta = (a + sh_top5[4]) + EPSF;
    float s_t = 0.0f, w = 0.0f;
    if (tid < rem) {                 // rem <= 256 so only waves 0..3 active
      s_t = a + sh_d[tid];
      w = s_t - delta;
      w = (w > 0.0f) ? w : 0.0f;
      if (rem <= 5) {
        int p = atomicAdd(&sh_nnz, 1);
        if (p < 8) { sh_cidx[p] = tid; sh_cw[p] = s_t; }   // attn_w = s branch
      } else if (w > 0.0f) {                               // <=4 by construction
        int p = atomicAdd(&sh_nnz, 1);
        if (p < 8) { sh_cidx[p] = tid; sh_cw[p] = w; }
      }
    }
    float pw = w;
    if (wid < 4) {
      #pragma unroll
      for (int off = 32; off > 0; off >>= 1) pw += __shfl_down(pw, off, 64);
      if (lane == 0) sh_redW[wid] = pw;
    }
    __syncthreads();                                        // S3

    // ---- Phase D: sparse gather from LDS history, h update, d_new ----
    const float wsum = (sh_redW[0] + sh_redW[1]) + (sh_redW[2] + sh_redW[3]);
    const float inv  = (rem <= 5) ? 1.0f : 1.0f / (wsum + EPSF);
    float pd = 0.0f;
    if (tid < 128) {
      int nz = sh_nnz; if (nz > 8) nz = 8;
      float attn = 0.0f;
      for (int k = 0; k < nz; ++k)
        attn = fmaf(sh_cw[k], ho[sh_cidx[k] * 128 + tid], attn);
      attn *= inv;
      float hn = sh_hcell[tid] + attn;
      sh_h[tid] = hn;
      ho[rem * 128 + tid] = hn;
      pd = ftanh(hn) * sh_wb[tid];
      if (i == 255) out[b * 128 + tid] = attn;             // final attn_c
    }
    if (i == 255 && tid < 256) {
      out[4096 + b * 256 + tid] = w * inv;                 // final attn_w
    }
    if (wid < 2) {
      #pragma unroll
      for (int off = 32; off > 0; off >>= 1) pd += __shfl_down(pd, off, 64);
      if (lane == 0) sh_redD[wid] = pd;
    }
    __syncthreads();                                        // S4
    if (tid == 0) {
      float dn = sh_redD[0] + sh_redD[1];
      sh_d[rem] = dn;
      float v = dn;                  // incremental sorted top-5 insert
      #pragma unroll
      for (int k = 0; k < 5; ++k) {
        if (v > sh_top5[k]) { float tmp = sh_top5[k]; sh_top5[k] = v; v = tmp; }
      }
    }
    // thread0's writes are separated from their readers by S1+S2 -> safe.
  }
}

extern "C" void kernel_launch(void* const* d_in, const int* in_sizes, int n_in,
                              void* d_out, int out_size, void* d_ws, size_t ws_size,
                              hipStream_t stream) {
  const float* x    = (const float*)d_in[0];  // (32,256,64)
  const float* W_ih = (const float*)d_in[1];  // (512,64)
  const float* W_hh = (const float*)d_in[2];  // (512,128)
  const float* b_ih = (const float*)d_in[3];  // (512,)
  const float* b_hh = (const float*)d_in[4];  // (512,)
  const float* w_t  = (const float*)d_in[5];  // (256,1)
  float* out = (float*)d_out;                 // [0:4096) attn_c, [4096:12288) attn_w

  float* xw = (float*)d_ws;                   // 32*256*512 fp32 = 16 MB

  xw_kernel<<<dim3(16, 32), 512, 0, stream>>>(x, W_ih, b_ih, b_hh, xw);
  lstm_attn<<<dim3(32), 512, 0, stream>>>(xw, W_hh, w_t, out);
}

// Round 5
// 631.898 us; speedup vs baseline: 1.3109x; 1.3109x over previous
//
#include <hip/hip_runtime.h>
#include <math.h>

#define NEGF -1000000000.0f
#define EPSF 1e-7f

// B=32, T=256, IN=64, H=128, 4H=512, TOP_K=5

typedef _Float16 half2v __attribute__((ext_vector_type(2)));

__device__ __forceinline__ float fsigmoid(float x) {
  return 1.0f / (1.0f + __expf(-x));               // overflow -> correct limit
}
__device__ __forceinline__ float ftanh(float x) {
  return 1.0f - 2.0f / (1.0f + __expf(2.0f * x));  // limits +-1: correct
}

__device__ __forceinline__ unsigned pack_h2(float a, float b) {
  half2v h; h.x = (_Float16)a; h.y = (_Float16)b;
  return __builtin_bit_cast(unsigned, h);
}
__device__ __forceinline__ unsigned pack_h2v(float2 p) { return pack_h2(p.x, p.y); }

__device__ __forceinline__ float dot2h(unsigned w, unsigned h, float acc) {
#if __has_builtin(__builtin_amdgcn_fdot2)
  return __builtin_amdgcn_fdot2(__builtin_bit_cast(half2v, w),
                                __builtin_bit_cast(half2v, h), acc, false);
#else
  half2v wv = __builtin_bit_cast(half2v, w);
  half2v hv = __builtin_bit_cast(half2v, h);
  return acc + (float)wv.x * (float)hv.x + (float)wv.y * (float)hv.y;
#endif
}

// Kernel 1: xw[b][t][g] = x[b][t] . W_ih[g] + (b_ih[g]+b_hh[g])
// grid (T/8, B, 2): gates split 256/block; thread owns HALF a W_ih row
// (8 float4 = 32 VGPRs) -> no spill at any register budget.
__global__ __launch_bounds__(512) void xw_kernel(
    const float* __restrict__ x, const float* __restrict__ W_ih,
    const float* __restrict__ b_ih, const float* __restrict__ b_hh,
    float* __restrict__ xw)
{
  const int t0 = blockIdx.x * 8;
  const int b  = blockIdx.y;
  const int gl = threadIdx.x & 255;
  const int g  = (blockIdx.z << 8) + gl;
  const int hf = threadIdx.x >> 8;           // k-half 0/1

  __shared__ float sx[8][64];                // 2 KB
  __shared__ float sp[2][256];
  {
    int idx = threadIdx.x;                   // 512 = 8*64 exactly
    int tt = idx >> 6, k = idx & 63;
    sx[tt][k] = x[(size_t)(b * 256 + t0 + tt) * 64 + k];
  }
  const float4* wr = (const float4*)(W_ih + (size_t)g * 64 + (hf << 5));
  float4 w0 = wr[0], w1 = wr[1], w2 = wr[2], w3 = wr[3],
         w4 = wr[4], w5 = wr[5], w6 = wr[6], w7 = wr[7];
  const float bias = (hf == 0) ? (b_ih[g] + b_hh[g]) : 0.0f;
  __syncthreads();
  for (int tt = 0; tt < 8; ++tt) {
    const float4* sx4 = (const float4*)(&sx[tt][hf << 5]);
    float a0 = 0.0f, a1 = 0.0f, a2 = 0.0f, a3 = 0.0f;
#define XSTEP(q) { float4 hv = sx4[q]; \
    a0 = fmaf(w##q.x, hv.x, a0); a1 = fmaf(w##q.y, hv.y, a1); \
    a2 = fmaf(w##q.z, hv.z, a2); a3 = fmaf(w##q.w, hv.w, a3); }
    XSTEP(0) XSTEP(1) XSTEP(2) XSTEP(3) XSTEP(4) XSTEP(5) XSTEP(6) XSTEP(7)
#undef XSTEP
    sp[hf][gl] = (a0 + a1) + (a2 + a3);
    __syncthreads();
    if (hf == 0)
      xw[(size_t)(b * 256 + t0 + tt) * 512 + g] = sp[0][gl] + sp[1][gl] + bias;
    __syncthreads();
  }
}

// Kernel 2: full recurrence, one block per batch element, 512 threads.
// Thread g owns gate g: 128 W_hh weights as fp16 half2 in 16 named uint4
// (= 64 VGPRs; fp32 needed 128 which exceeds what the RA will grant ->
// rounds 1-4 all re-loaded weights from memory every step).
// Matvec: v_dot2_f32_f16 against a packed-fp16 copy of h (sh_h2).
// State/history/scores stay fp32. Phases B-D run on wave 0 only
// (2 elements/lane, butterfly reductions) -> 2 barriers/step.
__global__
__attribute__((amdgpu_flat_work_group_size(512, 512), amdgpu_waves_per_eu(2, 2)))
void lstm_attn(
    const float* __restrict__ xw, const float* __restrict__ W_hh,
    const float* __restrict__ w_t, float* __restrict__ out)
{
  const int b   = blockIdx.x;
  const int tid = threadIdx.x;
  const int g   = tid;
  const int l   = tid & 63;       // lane
  const int wid = tid >> 6;

  __shared__ float    ho[257 * 128];   // fp32 h history (131584 B)
  __shared__ float    sh_part[512];    // gate preactivations
  __shared__ float    sh_d[257];       // cached tanh(h_t).w_b scores
  __shared__ unsigned sh_h2[64];       // h as packed half2 (matvec operand)
  __shared__ int      sh_nnz;
  __shared__ int      sh_cidx[8];
  __shared__ float    sh_cw[8];

  // ---- one-time: pack W_hh row g to fp16 in 16 named uint4 (64 VGPRs) ----
  const float2* wr2 = (const float2*)(W_hh + (size_t)g * 128);
#define LW(n, base) uint4 W##n; { \
    W##n.x = pack_h2v(wr2[base + 0]); W##n.y = pack_h2v(wr2[base + 1]); \
    W##n.z = pack_h2v(wr2[base + 2]); W##n.w = pack_h2v(wr2[base + 3]); }
  LW(0, 0)   LW(1, 4)   LW(2, 8)   LW(3, 12)
  LW(4, 16)  LW(5, 20)  LW(6, 24)  LW(7, 28)
  LW(8, 32)  LW(9, 36)  LW(10, 40) LW(11, 44)
  LW(12, 48) LW(13, 52) LW(14, 56) LW(15, 60)
#undef LW

  // ---- wave0 per-lane persistent state (elements j0=2l, j1=2l+1) ----
  const int j0 = 2 * l, j1 = 2 * l + 1;
  float c0 = 0.0f, c1 = 0.0f;
  float wa0 = 0.0f, wa1 = 0.0f, wb0 = 0.0f, wb1 = 0.0f;
  float t5_0 = 0.0f, t5_1 = NEGF, t5_2 = NEGF, t5_3 = NEGF, t5_4 = NEGF;
  if (wid == 0) {
    wa0 = w_t[j0];       wa1 = w_t[j1];
    wb0 = w_t[128 + j0]; wb1 = w_t[128 + j1];
    sh_h2[l] = 0u;                      // h(-1) = 0
    ho[j0] = 0.0f; ho[j1] = 0.0f;       // history row 0
  }
  if (tid == 0) { sh_d[0] = 0.0f; sh_nnz = 0; }
  __syncthreads();

  const float* xwb = xw + (size_t)b * 256 * 512;
  float xcur = xwb[g];

  for (int i = 0; i < 256; ++i) {
    const int rem = i + 1;

    // ---- matvec (all 512 threads): 64 dot2 from register weights ----
    float acc0 = xcur, acc1 = 0.0f, acc2 = 0.0f, acc3 = 0.0f;
    if (i < 255) xcur = xwb[(size_t)(i + 1) * 512 + g];   // prefetch
    const uint4* h4 = (const uint4*)sh_h2;
#define DOT4(W, q) { uint4 Hc = h4[q]; \
    acc0 = dot2h(W.x, Hc.x, acc0); acc1 = dot2h(W.y, Hc.y, acc1); \
    acc2 = dot2h(W.z, Hc.z, acc2); acc3 = dot2h(W.w, Hc.w, acc3); }
    DOT4(W0, 0)   DOT4(W1, 1)   DOT4(W2, 2)   DOT4(W3, 3)
    DOT4(W4, 4)   DOT4(W5, 5)   DOT4(W6, 6)   DOT4(W7, 7)
    DOT4(W8, 8)   DOT4(W9, 9)   DOT4(W10, 10) DOT4(W11, 11)
    DOT4(W12, 12) DOT4(W13, 13) DOT4(W14, 14) DOT4(W15, 15)
#undef DOT4
    sh_part[g] = (acc0 + acc1) + (acc2 + acc3);
    __syncthreads();                                      // S1

    if (wid == 0) {
      // ---- Phase B: LSTM cell (2 elements/lane) ----
      const float2* pp = (const float2*)sh_part;
      float2 pi = pp[l], pf = pp[64 + l], pg = pp[128 + l], po = pp[192 + l];
      c0 = fsigmoid(pf.x) * c0 + fsigmoid(pi.x) * ftanh(pg.x);
      c1 = fsigmoid(pf.y) * c1 + fsigmoid(pi.y) * ftanh(pg.y);
      float hc0 = fsigmoid(po.x) * ftanh(c0);
      float hc1 = fsigmoid(po.y) * ftanh(c1);
      float pa = ftanh(hc0) * wa0 + ftanh(hc1) * wa1;
      #pragma unroll
      for (int off = 1; off < 64; off <<= 1) pa += __shfl_xor(pa, off, 64);
      const float a = pa;

      // ---- Phase C: scores at t = l, l+64, l+128, l+192 ----
      const float delta = (a + t5_4) + EPSF;
      float wsum = 0.0f;
      float wv[4]; int tv[4]; bool sel[4]; float cval[4];
      #pragma unroll
      for (int m = 0; m < 4; ++m) {
        int t = l + 64 * m;
        tv[m] = t;
        float s = a + sh_d[t];
        float w = s - delta;
        w = (w > 0.0f) ? w : 0.0f;
        bool valid = (t < rem);
        wv[m] = valid ? w : 0.0f;
        wsum += wv[m];
        sel[m]  = valid && ((rem <= 5) || (w > 0.0f));
        cval[m] = (rem <= 5) ? s : w;
      }
      #pragma unroll
      for (int off = 1; off < 64; off <<= 1) wsum += __shfl_xor(wsum, off, 64);
      #pragma unroll
      for (int m = 0; m < 4; ++m) {
        if (sel[m]) {
          int p = atomicAdd(&sh_nnz, 1);
          if (p < 8) { sh_cidx[p] = tv[m]; sh_cw[p] = cval[m]; }
        }
      }
      const float inv = (rem <= 5) ? 1.0f : 1.0f / (wsum + EPSF);
      if (i == 255) {
        #pragma unroll
        for (int m = 0; m < 4; ++m)
          out[4096 + b * 256 + tv[m]] = wv[m] * inv;      // final attn_w
      }

      // ---- Phase D: sparse gather (fp32 LDS history), h update ----
      int nz = sh_nnz; if (nz > 8) nz = 8;                // same-wave: ordered
      float at0 = 0.0f, at1 = 0.0f;
      for (int k = 0; k < nz; ++k) {
        int   tt = sh_cidx[k];
        float cw = sh_cw[k];
        at0 = fmaf(cw, ho[tt * 128 + j0], at0);
        at1 = fmaf(cw, ho[tt * 128 + j1], at1);
      }
      at0 *= inv; at1 *= inv;
      float hn0 = hc0 + at0, hn1 = hc1 + at1;
      sh_h2[l] = pack_h2(hn0, hn1);
      ho[rem * 128 + j0] = hn0;
      ho[rem * 128 + j1] = hn1;
      if (i == 255) { out[b * 128 + j0] = at0; out[b * 128 + j1] = at1; }
      float pd = ftanh(hn0) * wb0 + ftanh(hn1) * wb1;
      #pragma unroll
      for (int off = 1; off < 64; off <<= 1) pd += __shfl_xor(pd, off, 64);
      if (l == 0) { sh_d[rem] = pd; sh_nnz = 0; }         // reset after use
      // replicated top-5 insert (identical in every lane)
      float v = pd;
      if (v > t5_0) { float t = t5_0; t5_0 = v; v = t; }
      if (v > t5_1) { float t = t5_1; t5_1 = v; v = t; }
      if (v > t5_2) { float t = t5_2; t5_2 = v; v = t; }
      if (v > t5_3) { float t = t5_3; t5_3 = v; v = t; }
      if (v > t5_4) { t5_4 = v; }
    }
    __syncthreads();                                      // S2
  }
}

extern "C" void kernel_launch(void* const* d_in, const int* in_sizes, int n_in,
                              void* d_out, int out_size, void* d_ws, size_t ws_size,
                              hipStream_t stream) {
  const float* x    = (const float*)d_in[0];  // (32,256,64)
  const float* W_ih = (const float*)d_in[1];  // (512,64)
  const float* W_hh = (const float*)d_in[2];  // (512,128)
  const float* b_ih = (const float*)d_in[3];  // (512,)
  const float* b_hh = (const float*)d_in[4];  // (512,)
  const float* w_t  = (const float*)d_in[5];  // (256,1)
  float* out = (float*)d_out;                 // [0:4096) attn_c, [4096:12288) attn_w

  float* xw = (float*)d_ws;                   // 32*256*512 fp32 = 16 MB

  xw_kernel<<<dim3(32, 32, 2), 512, 0, stream>>>(x, W_ih, b_ih, b_hh, xw);
  lstm_attn<<<dim3(32), 512, 0, stream>>>(xw, W_hh, w_t, out);
}

// Round 6
// 537.519 us; speedup vs baseline: 1.5411x; 1.1756x over previous
//
#include <hip/hip_runtime.h>
#include <math.h>

#define NEGF -1000000000.0f
#define EPSF 1e-7f

// B=32, T=256, IN=64, H=128, 4H=512, TOP_K=5

__device__ __forceinline__ float fsigmoid(float x) {
  return 1.0f / (1.0f + __expf(-x));               // overflow -> correct limit
}
__device__ __forceinline__ float ftanh(float x) {
  return 1.0f - 2.0f / (1.0f + __expf(2.0f * x));  // limits +-1: correct
}

// wave64 all-reduce sum via DPP (row_shr 1/2/4/8 + row_bcast 15/31), ~35 cyc
// vs ~250 for a ds_bpermute shfl butterfly. Result broadcast via readlane.
__device__ __forceinline__ float wave_allsum(float v) {
#if __has_builtin(__builtin_amdgcn_update_dpp) && __has_builtin(__builtin_amdgcn_readlane)
  float f = v;
#define DPPSTEP(ctrl, rmask) { \
    int t = __builtin_amdgcn_update_dpp(0, __builtin_bit_cast(int, f), \
                                        ctrl, rmask, 0xf, true); \
    f += __builtin_bit_cast(float, t); }
  DPPSTEP(0x111, 0xf)   // row_shr:1
  DPPSTEP(0x112, 0xf)   // row_shr:2
  DPPSTEP(0x114, 0xf)   // row_shr:4
  DPPSTEP(0x118, 0xf)   // row_shr:8  -> lane15 of each row has row sum
  DPPSTEP(0x142, 0xa)   // row_bcast:15 into rows 1,3
  DPPSTEP(0x143, 0x8)   // row_bcast:31 into row 3 -> lane 63 = total
#undef DPPSTEP
  return __builtin_bit_cast(float,
      __builtin_amdgcn_readlane(__builtin_bit_cast(int, f), 63));
#else
  for (int off = 1; off < 64; off <<= 1) v += __shfl_xor(v, off, 64);
  return v;
#endif
}

// Kernel 1: xw[b][t][g] = x[b][t] . W_ih[g] + (b_ih[g]+b_hh[g])
// grid (T/8, B, 2): gates split 256/block; thread owns HALF a W_ih row
// (8 float4 = 32 VGPRs) -> no spill at any register budget.
__global__ __launch_bounds__(512) void xw_kernel(
    const float* __restrict__ x, const float* __restrict__ W_ih,
    const float* __restrict__ b_ih, const float* __restrict__ b_hh,
    float* __restrict__ xw)
{
  const int t0 = blockIdx.x * 8;
  const int b  = blockIdx.y;
  const int gl = threadIdx.x & 255;
  const int g  = (blockIdx.z << 8) + gl;
  const int hf = threadIdx.x >> 8;           // k-half 0/1

  __shared__ float sx[8][64];                // 2 KB
  __shared__ float sp[2][256];
  {
    int idx = threadIdx.x;                   // 512 = 8*64 exactly
    int tt = idx >> 6, k = idx & 63;
    sx[tt][k] = x[(size_t)(b * 256 + t0 + tt) * 64 + k];
  }
  const float4* wr = (const float4*)(W_ih + (size_t)g * 64 + (hf << 5));
  float4 w0 = wr[0], w1 = wr[1], w2 = wr[2], w3 = wr[3],
         w4 = wr[4], w5 = wr[5], w6 = wr[6], w7 = wr[7];
  const float bias = (hf == 0) ? (b_ih[g] + b_hh[g]) : 0.0f;
  __syncthreads();
  for (int tt = 0; tt < 8; ++tt) {
    const float4* sx4 = (const float4*)(&sx[tt][hf << 5]);
    float a0 = 0.0f, a1 = 0.0f, a2 = 0.0f, a3 = 0.0f;
#define XSTEP(q) { float4 hv = sx4[q]; \
    a0 = fmaf(w##q.x, hv.x, a0); a1 = fmaf(w##q.y, hv.y, a1); \
    a2 = fmaf(w##q.z, hv.z, a2); a3 = fmaf(w##q.w, hv.w, a3); }
    XSTEP(0) XSTEP(1) XSTEP(2) XSTEP(3) XSTEP(4) XSTEP(5) XSTEP(6) XSTEP(7)
#undef XSTEP
    sp[hf][gl] = (a0 + a1) + (a2 + a3);
    __syncthreads();
    if (hf == 0)
      xw[(size_t)(b * 256 + t0 + tt) * 512 + g] = sp[0][gl] + sp[1][gl] + bias;
    __syncthreads();
  }
}

// Kernel 2: full recurrence, one block per batch element, 1024 threads.
// Thread t: K-chunk q = t>>8 (32 of 128 h values), gates (t&255), (t&255)+256:
// 64 fp32 weights in 16 named float4s. amdgpu_waves_per_eu(4,4) sets the
// register cap to 128 (round 4 evidence); need ~95 -> resident, no remat.
// Phases B-D on wave 0 only (2 h-elements/lane, DPP reductions, fixed-5
// gather): 2 barriers/step. fp32 everywhere (round-5 fp16 absmax 0.246
// was too close to the 0.29 threshold).
__global__
__attribute__((amdgpu_flat_work_group_size(1024, 1024), amdgpu_waves_per_eu(4, 4)))
void lstm_attn(
    const float* __restrict__ xw, const float* __restrict__ W_hh,
    const float* __restrict__ w_t, float* __restrict__ out)
{
  const int b   = blockIdx.x;
  const int tid = threadIdx.x;
  const int l   = tid & 63;       // lane
  const int wid = tid >> 6;
  const int p   = tid & 255;      // gate-pair id
  const int q   = tid >> 8;       // K-chunk 0..3 (wave-uniform)
  const int gA  = p;
  const int gB  = p + 256;

  __shared__ float ho[257 * 128];     // fp32 h history (131584 B)
  __shared__ float sh_part[4 * 512];  // gate partials [q][gate] (8 KB)
  __shared__ float sh_h[128];
  __shared__ float sh_d[257];         // cached tanh(h_t).w_b scores
  __shared__ int   sh_nnz;
  __shared__ int   sh_cidx[8];
  __shared__ float sh_cw[8];

  // one-time weight load: 16 named float4 = 64 VGPRs
  const float4* pA = (const float4*)(W_hh + (size_t)gA * 128 + (q << 5));
  const float4* pB = (const float4*)(W_hh + (size_t)gB * 128 + (q << 5));
  float4 wA0 = pA[0], wA1 = pA[1], wA2 = pA[2], wA3 = pA[3],
         wA4 = pA[4], wA5 = pA[5], wA6 = pA[6], wA7 = pA[7];
  float4 wB0 = pB[0], wB1 = pB[1], wB2 = pB[2], wB3 = pB[3],
         wB4 = pB[4], wB5 = pB[5], wB6 = pB[6], wB7 = pB[7];

  // wave0 per-lane persistent state (h elements j0=2l, j1=2l+1)
  const int j0 = 2 * l, j1 = 2 * l + 1;
  float c0 = 0.0f, c1 = 0.0f;
  float wa0 = 0.0f, wa1 = 0.0f, wb0 = 0.0f, wb1 = 0.0f;
  float t5_0 = 0.0f, t5_1 = NEGF, t5_2 = NEGF, t5_3 = NEGF, t5_4 = NEGF;
  if (wid == 0) {
    wa0 = w_t[j0];       wa1 = w_t[j1];
    wb0 = w_t[128 + j0]; wb1 = w_t[128 + j1];
    sh_h[j0] = 0.0f; sh_h[j1] = 0.0f;   // h(-1) = 0
    ho[j0]   = 0.0f; ho[j1]   = 0.0f;   // history row 0
  }
  if (tid == 0) { sh_d[0] = 0.0f; sh_nnz = 0; }
  __syncthreads();

  const float* xwb = xw + (size_t)b * 256 * 512;
  float xcurA = 0.0f, xcurB = 0.0f;
  if (q == 0) { xcurA = xwb[gA]; xcurB = xwb[gB]; }

  for (int i = 0; i < 256; ++i) {
    const int rem = i + 1;

    // ---- Phase A: gate partials (64 FMAs from named-VGPR fp32 weights) ----
    float aA0 = xcurA, aA1 = 0.0f, aB0 = xcurB, aB1 = 0.0f;
    if (q == 0 && i < 255) {          // prefetch next step's xw
      xcurA = xwb[(size_t)(i + 1) * 512 + gA];
      xcurB = xwb[(size_t)(i + 1) * 512 + gB];
    }
    const float4* hh4 = (const float4*)(sh_h + (q << 5));
#define LSTEP(j) { float4 hv = hh4[j]; \
    aA0 = fmaf(wA##j.x, hv.x, aA0); aA1 = fmaf(wA##j.y, hv.y, aA1); \
    aA0 = fmaf(wA##j.z, hv.z, aA0); aA1 = fmaf(wA##j.w, hv.w, aA1); \
    aB0 = fmaf(wB##j.x, hv.x, aB0); aB1 = fmaf(wB##j.y, hv.y, aB1); \
    aB0 = fmaf(wB##j.z, hv.z, aB0); aB1 = fmaf(wB##j.w, hv.w, aB1); }
    LSTEP(0) LSTEP(1) LSTEP(2) LSTEP(3) LSTEP(4) LSTEP(5) LSTEP(6) LSTEP(7)
#undef LSTEP
    sh_part[(q << 9) + gA] = aA0 + aA1;
    sh_part[(q << 9) + gB] = aB0 + aB1;
    __syncthreads();                                      // S1

    if (wid == 0) {
      // ---- housekeeping + early loads (hide LDS latency) ----
      if (l < 8) { sh_cidx[l] = 0; sh_cw[l] = 0.0f; }     // pad gather slots
      if (l == 0) sh_nnz = 0;
      float d0 = sh_d[l], d1 = sh_d[l + 64],
            d2 = sh_d[l + 128], d3 = sh_d[l + 192];

      // ---- Phase B: LSTM cell (2 elements/lane) ----
#define GSUM(base) ({ \
      float2 x0 = ((const float2*)(sh_part        + (base)))[l]; \
      float2 x1 = ((const float2*)(sh_part +  512 + (base)))[l]; \
      float2 x2 = ((const float2*)(sh_part + 1024 + (base)))[l]; \
      float2 x3 = ((const float2*)(sh_part + 1536 + (base)))[l]; \
      float2 r; r.x = (x0.x + x1.x) + (x2.x + x3.x); \
      r.y = (x0.y + x1.y) + (x2.y + x3.y); r; })
      float2 Pi = GSUM(0), Pf = GSUM(128), Pg = GSUM(256), Po = GSUM(384);
#undef GSUM
      c0 = fsigmoid(Pf.x) * c0 + fsigmoid(Pi.x) * ftanh(Pg.x);
      c1 = fsigmoid(Pf.y) * c1 + fsigmoid(Pi.y) * ftanh(Pg.y);
      float hc0 = fsigmoid(Po.x) * ftanh(c0);
      float hc1 = fsigmoid(Po.y) * ftanh(c1);
      const float a = wave_allsum(ftanh(hc0) * wa0 + ftanh(hc1) * wa1);

      // ---- Phase C: scores at t = l, l+64, l+128, l+192 ----
      const float delta = (a + t5_4) + EPSF;
      float dv[4] = {d0, d1, d2, d3};
      float wv[4]; float wsum = 0.0f;
      #pragma unroll
      for (int m = 0; m < 4; ++m) {
        int t = l + 64 * m;
        float s = a + dv[m];
        float w = s - delta;
        w = (w > 0.0f) ? w : 0.0f;
        bool valid = (t < rem);
        wv[m] = valid ? w : 0.0f;
        wsum += wv[m];
        bool sel = valid && ((rem <= 5) || (w > 0.0f));
        if (sel) {
          int pp = atomicAdd(&sh_nnz, 1);
          float cv = (rem <= 5) ? s : w;
          if (pp < 8) { sh_cidx[pp] = t; sh_cw[pp] = cv; }
        }
      }
      wsum = wave_allsum(wsum);
      const float inv = (rem <= 5) ? 1.0f : 1.0f / (wsum + EPSF);
      if (i == 255) {
        #pragma unroll
        for (int m = 0; m < 4; ++m)
          out[4096 + b * 256 + (l + 64 * m)] = wv[m] * inv;  // final attn_w
      }

      // ---- Phase D: fixed-5 gather (nz<=5 provable; slots padded w=0) ----
      int   i0 = sh_cidx[0], i1 = sh_cidx[1], i2 = sh_cidx[2],
            i3 = sh_cidx[3], i4 = sh_cidx[4];
      float g0 = sh_cw[0], g1 = sh_cw[1], g2 = sh_cw[2],
            g3 = sh_cw[3], g4 = sh_cw[4];
      float at0 = g0 * ho[i0 * 128 + j0];
      float at1 = g0 * ho[i0 * 128 + j1];
      at0 = fmaf(g1, ho[i1 * 128 + j0], at0);
      at1 = fmaf(g1, ho[i1 * 128 + j1], at1);
      at0 = fmaf(g2, ho[i2 * 128 + j0], at0);
      at1 = fmaf(g2, ho[i2 * 128 + j1], at1);
      at0 = fmaf(g3, ho[i3 * 128 + j0], at0);
      at1 = fmaf(g3, ho[i3 * 128 + j1], at1);
      at0 = fmaf(g4, ho[i4 * 128 + j0], at0);
      at1 = fmaf(g4, ho[i4 * 128 + j1], at1);
      at0 *= inv; at1 *= inv;
      float hn0 = hc0 + at0, hn1 = hc1 + at1;
      sh_h[j0] = hn0; sh_h[j1] = hn1;
      ho[rem * 128 + j0] = hn0;
      ho[rem * 128 + j1] = hn1;
      if (i == 255) { out[b * 128 + j0] = at0; out[b * 128 + j1] = at1; }
      float dn = wave_allsum(ftanh(hn0) * wb0 + ftanh(hn1) * wb1);
      if (l == 0) sh_d[rem] = dn;
      // replicated top-5 insert (identical in every lane of wave 0)
      float v = dn;
      if (v > t5_0) { float t = t5_0; t5_0 = v; v = t; }
      if (v > t5_1) { float t = t5_1; t5_1 = v; v = t; }
      if (v > t5_2) { float t = t5_2; t5_2 = v; v = t; }
      if (v > t5_3) { float t = t5_3; t5_3 = v; v = t; }
      if (v > t5_4) { t5_4 = v; }
    }
    __syncthreads();                                      // S2
  }
}

extern "C" void kernel_launch(void* const* d_in, const int* in_sizes, int n_in,
                              void* d_out, int out_size, void* d_ws, size_t ws_size,
                              hipStream_t stream) {
  const float* x    = (const float*)d_in[0];  // (32,256,64)
  const float* W_ih = (const float*)d_in[1];  // (512,64)
  const float* W_hh = (const float*)d_in[2];  // (512,128)
  const float* b_ih = (const float*)d_in[3];  // (512,)
  const float* b_hh = (const float*)d_in[4];  // (512,)
  const float* w_t  = (const float*)d_in[5];  // (256,1)
  float* out = (float*)d_out;                 // [0:4096) attn_c, [4096:12288) attn_w

  float* xw = (float*)d_ws;                   // 32*256*512 fp32 = 16 MB

  xw_kernel<<<dim3(32, 32, 2), 512, 0, stream>>>(x, W_ih, b_ih, b_hh, xw);
  lstm_attn<<<dim3(32), 1024, 0, stream>>>(xw, W_hh, w_t, out);
}